// Round 4
// baseline (173.036 us; speedup 1.0000x reference)
//
#include <hip/hip_runtime.h>

// Weighted3DTransformNormLoss — MI355X (gfx950)
// loss = 0.5/size * sum_{b,k,h,w} mask * ||(R-I)p + (t - tf)||^2 / (0.5||tf||^2 + eps)
//
// R4: persistent-style software-pipelined streaming. 800 blocks, each pinned
// to one batch, 3 chunks of 1024 px each, register double-buffer so 14
// float4 loads stay in flight while computing the previous chunk.

constexpr int BATCH = 32;
constexpr int KK    = 8;
constexpr int H     = 240;
constexpr int W     = 320;
constexpr int HW    = H * W;                 // 76800
constexpr float EPS = 0.001f;
constexpr float SCALE = 0.5f / (float)(BATCH * 3 * HW);

constexpr int PIX_PER_THREAD = 4;
constexpr int CHUNK          = 256 * PIX_PER_THREAD;   // 1024 px
constexpr int CHUNKS_PER_B   = HW / CHUNK;             // 75
constexpr int BLOCKS_PER_B   = 25;
constexpr int ITERS          = CHUNKS_PER_B / BLOCKS_PER_B;  // 3
constexpr int NBLOCKS        = BATCH * BLOCKS_PER_B;   // 800

struct Chunk { float4 v[14]; };   // p0,p1,p2,f0,f1,f2,m0..m7

__device__ __forceinline__ void load_chunk(Chunk& c,
    const float* __restrict__ pb, const float* __restrict__ fb,
    const float* __restrict__ mb, int base)
{
    c.v[0] = *(const float4*)(pb + 0 * HW + base);
    c.v[1] = *(const float4*)(pb + 1 * HW + base);
    c.v[2] = *(const float4*)(pb + 2 * HW + base);
    c.v[3] = *(const float4*)(fb + 0 * HW + base);
    c.v[4] = *(const float4*)(fb + 1 * HW + base);
    c.v[5] = *(const float4*)(fb + 2 * HW + base);
    #pragma unroll
    for (int k = 0; k < KK; ++k)
        c.v[6 + k] = *(const float4*)(mb + k * HW + base);
}

__device__ __forceinline__ float compute_chunk(const Chunk& c, const float* sT)
{
    const float P0[4] = {c.v[0].x, c.v[0].y, c.v[0].z, c.v[0].w};
    const float P1[4] = {c.v[1].x, c.v[1].y, c.v[1].z, c.v[1].w};
    const float P2[4] = {c.v[2].x, c.v[2].y, c.v[2].z, c.v[2].w};
    const float F0[4] = {c.v[3].x, c.v[3].y, c.v[3].z, c.v[3].w};
    const float F1[4] = {c.v[4].x, c.v[4].y, c.v[4].z, c.v[4].w};
    const float F2[4] = {c.v[5].x, c.v[5].y, c.v[5].z, c.v[5].w};

    float accp[4] = {0.f, 0.f, 0.f, 0.f};

    #pragma unroll
    for (int k = 0; k < KK; ++k) {
        const float m00 = sT[k*12+0], m01 = sT[k*12+1], m02 = sT[k*12+2],  t0 = sT[k*12+3];
        const float m10 = sT[k*12+4], m11 = sT[k*12+5], m12 = sT[k*12+6],  t1 = sT[k*12+7];
        const float m20 = sT[k*12+8], m21 = sT[k*12+9], m22 = sT[k*12+10], t2 = sT[k*12+11];
        const float MK[4] = {c.v[6+k].x, c.v[6+k].y, c.v[6+k].z, c.v[6+k].w};

        #pragma unroll
        for (int e = 0; e < 4; ++e) {
            float d0 = fmaf(m00, P0[e], fmaf(m01, P1[e], fmaf(m02, P2[e], t0 - F0[e])));
            float d1 = fmaf(m10, P0[e], fmaf(m11, P1[e], fmaf(m12, P2[e], t1 - F1[e])));
            float d2 = fmaf(m20, P0[e], fmaf(m21, P1[e], fmaf(m22, P2[e], t2 - F2[e])));
            float sq = fmaf(d0, d0, fmaf(d1, d1, d2 * d2));
            accp[e]  = fmaf(MK[e], sq, accp[e]);
        }
    }

    float acc = 0.f;
    #pragma unroll
    for (int e = 0; e < 4; ++e) {
        float sig = fmaf(0.5f * F0[e], F0[e],
                    fmaf(0.5f * F1[e], F1[e],
                    fmaf(0.5f * F2[e], F2[e], EPS)));
        acc += accp[e] / sig;
    }
    return acc;
}

__global__ __launch_bounds__(256, 3) void w3d_loss_kernel(
    const float* __restrict__ pts,     // [B,3,H,W]
    const float* __restrict__ masks,   // [B,K,H,W]
    const float* __restrict__ tfms,    // [B,K,3,4]
    const float* __restrict__ flows,   // [B,3,H,W]
    float* __restrict__ partials)      // [NBLOCKS]
{
    __shared__ float sT[KK * 12];
    __shared__ float sWave[4];

    const int b   = blockIdx.x / BLOCKS_PER_B;
    const int sub = blockIdx.x % BLOCKS_PER_B;
    const int tid = threadIdx.x;

    if (tid < KK * 12) {
        float v = tfms[b * KK * 12 + tid];
        int j  = tid % 12;
        int i  = j >> 2;
        int jj = j & 3;
        if (jj < 3 && i == jj) v -= 1.0f;
        sT[tid] = v;
    }
    __syncthreads();

    const float* pb = pts   + (size_t)b * 3  * HW;
    const float* fb = flows + (size_t)b * 3  * HW;
    const float* mb = masks + (size_t)b * KK * HW;

    // chunk index for iteration i: sub + i*BLOCKS_PER_B, base px = chunk*CHUNK + tid*4
    Chunk cur, nxt;
    load_chunk(cur, pb, fb, mb, sub * CHUNK + tid * PIX_PER_THREAD);

    float acc = 0.f;
    #pragma unroll
    for (int it = 0; it < ITERS; ++it) {
        if (it + 1 < ITERS) {
            int base = (sub + (it + 1) * BLOCKS_PER_B) * CHUNK + tid * PIX_PER_THREAD;
            load_chunk(nxt, pb, fb, mb, base);   // issue next-chunk loads first
        }
        acc += compute_chunk(cur, sT);           // waits only on cur's (older) loads
        cur = nxt;                               // SSA rename, no v_movs after unroll
    }

    #pragma unroll
    for (int off = 32; off > 0; off >>= 1) acc += __shfl_down(acc, off);
    if ((tid & 63) == 0) sWave[tid >> 6] = acc;
    __syncthreads();
    if (tid == 0) {
        float s = (sWave[0] + sWave[1]) + (sWave[2] + sWave[3]);
        partials[blockIdx.x] = s;
    }
}

__global__ __launch_bounds__(256) void reduce_kernel(
    const float* __restrict__ partials, float* __restrict__ out)
{
    __shared__ float sWave[4];
    const int tid = threadIdx.x;

    float acc = 0.f;
    for (int i = tid; i < NBLOCKS; i += 256) acc += partials[i];

    #pragma unroll
    for (int off = 32; off > 0; off >>= 1) acc += __shfl_down(acc, off);
    if ((tid & 63) == 0) sWave[tid >> 6] = acc;
    __syncthreads();
    if (tid == 0) {
        float s = (sWave[0] + sWave[1]) + (sWave[2] + sWave[3]);
        out[0] = s * SCALE;
    }
}

extern "C" void kernel_launch(void* const* d_in, const int* in_sizes, int n_in,
                              void* d_out, int out_size, void* d_ws, size_t ws_size,
                              hipStream_t stream) {
    const float* pts   = (const float*)d_in[0];
    const float* masks = (const float*)d_in[1];
    const float* tfms  = (const float*)d_in[2];
    const float* flows = (const float*)d_in[3];
    float* out      = (float*)d_out;
    float* partials = (float*)d_ws;

    w3d_loss_kernel<<<NBLOCKS, 256, 0, stream>>>(pts, masks, tfms, flows, partials);
    reduce_kernel<<<1, 256, 0, stream>>>(partials, out);
}

// Round 6
// 165.868 us; speedup vs baseline: 1.0432x; 1.0432x over previous
//
#include <hip/hip_runtime.h>

// Weighted3DTransformNormLoss — MI355X (gfx950)
// loss = 0.5/size * sum_{b,k,h,w} mask * ||(R-I)p + (t - tf)||^2 / (0.5||tf||^2 + eps)
//
// R5 (resubmit after broker timeout): max-TLP variant. 2 px/thread (float2,
// 8B/lane), payload = 28 VGPR so ALL 14 loads hoist; 4800 blocks -> ~19
// blocks/CU, target 8 waves/SIMD.

constexpr int BATCH = 32;
constexpr int KK    = 8;
constexpr int H     = 240;
constexpr int W     = 320;
constexpr int HW    = H * W;                 // 76800
constexpr float EPS = 0.001f;
constexpr float SCALE = 0.5f / (float)(BATCH * 3 * HW);

constexpr int PIX_PER_THREAD = 2;
constexpr int BLOCKS_X = HW / (256 * PIX_PER_THREAD);    // 150
constexpr int NPARTIAL = BLOCKS_X * BATCH;               // 4800

__global__ __launch_bounds__(256, 8) void w3d_loss_kernel(
    const float* __restrict__ pts,     // [B,3,H,W]
    const float* __restrict__ masks,   // [B,K,H,W]
    const float* __restrict__ tfms,    // [B,K,3,4]
    const float* __restrict__ flows,   // [B,3,H,W]
    float* __restrict__ partials)      // [NPARTIAL]
{
    __shared__ float sT[KK * 12];
    __shared__ float sWave[4];

    const int b   = blockIdx.y;
    const int tid = threadIdx.x;

    if (tid < KK * 12) {
        float v = tfms[b * KK * 12 + tid];
        int j  = tid % 12;
        int i  = j >> 2;
        int jj = j & 3;
        if (jj < 3 && i == jj) v -= 1.0f;
        sT[tid] = v;
    }
    __syncthreads();

    const int base = (blockIdx.x * 256 + tid) * PIX_PER_THREAD;
    const float* pb = pts   + (size_t)b * 3  * HW;
    const float* fb = flows + (size_t)b * 3  * HW;
    const float* mb = masks + (size_t)b * KK * HW;

    // ---- all 14 float2 loads (28 VGPRs payload) issued up front ----
    const float2 p0 = *(const float2*)(pb + 0 * HW + base);
    const float2 p1 = *(const float2*)(pb + 1 * HW + base);
    const float2 p2 = *(const float2*)(pb + 2 * HW + base);
    const float2 f0 = *(const float2*)(fb + 0 * HW + base);
    const float2 f1 = *(const float2*)(fb + 1 * HW + base);
    const float2 f2 = *(const float2*)(fb + 2 * HW + base);

    float2 mk[KK];
    #pragma unroll
    for (int k = 0; k < KK; ++k)
        mk[k] = *(const float2*)(mb + k * HW + base);

    const float P0[2] = {p0.x, p0.y};
    const float P1[2] = {p1.x, p1.y};
    const float P2[2] = {p2.x, p2.y};
    const float F0[2] = {f0.x, f0.y};
    const float F1[2] = {f1.x, f1.y};
    const float F2[2] = {f2.x, f2.y};

    float accp[2] = {0.f, 0.f};

    #pragma unroll
    for (int k = 0; k < KK; ++k) {
        const float m00 = sT[k*12+0], m01 = sT[k*12+1], m02 = sT[k*12+2],  t0 = sT[k*12+3];
        const float m10 = sT[k*12+4], m11 = sT[k*12+5], m12 = sT[k*12+6],  t1 = sT[k*12+7];
        const float m20 = sT[k*12+8], m21 = sT[k*12+9], m22 = sT[k*12+10], t2 = sT[k*12+11];
        const float MK[2] = {mk[k].x, mk[k].y};

        #pragma unroll
        for (int e = 0; e < 2; ++e) {
            float d0 = fmaf(m00, P0[e], fmaf(m01, P1[e], fmaf(m02, P2[e], t0 - F0[e])));
            float d1 = fmaf(m10, P0[e], fmaf(m11, P1[e], fmaf(m12, P2[e], t1 - F1[e])));
            float d2 = fmaf(m20, P0[e], fmaf(m21, P1[e], fmaf(m22, P2[e], t2 - F2[e])));
            float sq = fmaf(d0, d0, fmaf(d1, d1, d2 * d2));
            accp[e]  = fmaf(MK[e], sq, accp[e]);
        }
    }

    float acc = 0.f;
    #pragma unroll
    for (int e = 0; e < 2; ++e) {
        float sig = fmaf(0.5f * F0[e], F0[e],
                    fmaf(0.5f * F1[e], F1[e],
                    fmaf(0.5f * F2[e], F2[e], EPS)));
        acc += accp[e] / sig;
    }

    #pragma unroll
    for (int off = 32; off > 0; off >>= 1) acc += __shfl_down(acc, off);
    if ((tid & 63) == 0) sWave[tid >> 6] = acc;
    __syncthreads();
    if (tid == 0) {
        float s = (sWave[0] + sWave[1]) + (sWave[2] + sWave[3]);
        partials[blockIdx.y * gridDim.x + blockIdx.x] = s;
    }
}

__global__ __launch_bounds__(256) void reduce_kernel(
    const float* __restrict__ partials, float* __restrict__ out)
{
    __shared__ float sWave[4];
    const int tid = threadIdx.x;

    float acc = 0.f;
    for (int i = tid; i < NPARTIAL; i += 256) acc += partials[i];

    #pragma unroll
    for (int off = 32; off > 0; off >>= 1) acc += __shfl_down(acc, off);
    if ((tid & 63) == 0) sWave[tid >> 6] = acc;
    __syncthreads();
    if (tid == 0) {
        float s = (sWave[0] + sWave[1]) + (sWave[2] + sWave[3]);
        out[0] = s * SCALE;
    }
}

extern "C" void kernel_launch(void* const* d_in, const int* in_sizes, int n_in,
                              void* d_out, int out_size, void* d_ws, size_t ws_size,
                              hipStream_t stream) {
    const float* pts   = (const float*)d_in[0];
    const float* masks = (const float*)d_in[1];
    const float* tfms  = (const float*)d_in[2];
    const float* flows = (const float*)d_in[3];
    float* out      = (float*)d_out;
    float* partials = (float*)d_ws;    // 4800 floats (19.2 KB) scratch

    dim3 grid(BLOCKS_X, BATCH);        // (150, 32) = 4800 blocks
    w3d_loss_kernel<<<grid, 256, 0, stream>>>(pts, masks, tfms, flows, partials);
    reduce_kernel<<<1, 256, 0, stream>>>(partials, out);
}

// Round 7
// 164.051 us; speedup vs baseline: 1.0548x; 1.0111x over previous
//
#include <hip/hip_runtime.h>

// Weighted3DTransformNormLoss — MI355X (gfx950)
// loss = 0.5/size * sum_{b,k,h,w} mask * ||(R-I)p + (t - tf)||^2 / (0.5||tf||^2 + eps)
//
// R7: force memory-level parallelism. hipcc keeps sinking loads to uses
// (VGPR 28-36 across R2/R4/R5 => ~3 loads in flight, serial latency epochs).
// Fix: one asm volatile consuming ALL 14 load results -> compiler must issue
// all 14 global_load_dwordx4, then a single s_waitcnt vmcnt(0).

typedef float f32x4 __attribute__((ext_vector_type(4)));

constexpr int BATCH = 32;
constexpr int KK    = 8;
constexpr int H     = 240;
constexpr int W     = 320;
constexpr int HW    = H * W;                 // 76800
constexpr float EPS = 0.001f;
constexpr float SCALE = 0.5f / (float)(BATCH * 3 * HW);

constexpr int PIX_PER_THREAD = 4;
constexpr int BLOCKS_X = HW / (256 * PIX_PER_THREAD);    // 75
constexpr int NPARTIAL = BLOCKS_X * BATCH;               // 2400

__global__ __launch_bounds__(256, 4) void w3d_loss_kernel(
    const float* __restrict__ pts,     // [B,3,H,W]
    const float* __restrict__ masks,   // [B,K,H,W]
    const float* __restrict__ tfms,    // [B,K,3,4]
    const float* __restrict__ flows,   // [B,3,H,W]
    float* __restrict__ partials)      // [NPARTIAL]
{
    __shared__ float sT[KK * 12];
    __shared__ float sWave[4];

    const int b   = blockIdx.y;
    const int tid = threadIdx.x;

    if (tid < KK * 12) {
        float v = tfms[b * KK * 12 + tid];
        int j  = tid % 12;
        int i  = j >> 2;
        int jj = j & 3;
        if (jj < 3 && i == jj) v -= 1.0f;
        sT[tid] = v;
    }
    __syncthreads();

    const int base = (blockIdx.x * 256 + tid) * PIX_PER_THREAD;
    const float* pb = pts   + (size_t)b * 3  * HW;
    const float* fb = flows + (size_t)b * 3  * HW;
    const float* mb = masks + (size_t)b * KK * HW;

    // ---- issue ALL 14 float4 loads; no use until the asm fence below ----
    f32x4 p0 = *(const f32x4*)(pb + 0 * HW + base);
    f32x4 p1 = *(const f32x4*)(pb + 1 * HW + base);
    f32x4 p2 = *(const f32x4*)(pb + 2 * HW + base);
    f32x4 f0 = *(const f32x4*)(fb + 0 * HW + base);
    f32x4 f1 = *(const f32x4*)(fb + 1 * HW + base);
    f32x4 f2 = *(const f32x4*)(fb + 2 * HW + base);
    f32x4 m0 = *(const f32x4*)(mb + 0 * HW + base);
    f32x4 m1 = *(const f32x4*)(mb + 1 * HW + base);
    f32x4 m2 = *(const f32x4*)(mb + 2 * HW + base);
    f32x4 m3 = *(const f32x4*)(mb + 3 * HW + base);
    f32x4 m4 = *(const f32x4*)(mb + 4 * HW + base);
    f32x4 m5 = *(const f32x4*)(mb + 5 * HW + base);
    f32x4 m6 = *(const f32x4*)(mb + 6 * HW + base);
    f32x4 m7 = *(const f32x4*)(mb + 7 * HW + base);

    // Single first-use point: all 14 loads must be issued before this, and
    // exactly one s_waitcnt vmcnt(0) lands here. Keeps 224 B/thread in flight.
    asm volatile("" ::
        "v"(p0), "v"(p1), "v"(p2), "v"(f0), "v"(f1), "v"(f2),
        "v"(m0), "v"(m1), "v"(m2), "v"(m3), "v"(m4), "v"(m5), "v"(m6), "v"(m7));

    const float P0[4] = {p0.x, p0.y, p0.z, p0.w};
    const float P1[4] = {p1.x, p1.y, p1.z, p1.w};
    const float P2[4] = {p2.x, p2.y, p2.z, p2.w};
    const float F0[4] = {f0.x, f0.y, f0.z, f0.w};
    const float F1[4] = {f1.x, f1.y, f1.z, f1.w};
    const float F2[4] = {f2.x, f2.y, f2.z, f2.w};
    const f32x4 MKV[KK] = {m0, m1, m2, m3, m4, m5, m6, m7};

    float accp[4] = {0.f, 0.f, 0.f, 0.f};

    #pragma unroll
    for (int k = 0; k < KK; ++k) {
        const float m00 = sT[k*12+0], m01 = sT[k*12+1], m02 = sT[k*12+2],  t0 = sT[k*12+3];
        const float m10 = sT[k*12+4], m11 = sT[k*12+5], m12 = sT[k*12+6],  t1 = sT[k*12+7];
        const float m20 = sT[k*12+8], m21 = sT[k*12+9], m22 = sT[k*12+10], t2 = sT[k*12+11];
        const float MK[4] = {MKV[k].x, MKV[k].y, MKV[k].z, MKV[k].w};

        #pragma unroll
        for (int e = 0; e < 4; ++e) {
            float d0 = fmaf(m00, P0[e], fmaf(m01, P1[e], fmaf(m02, P2[e], t0 - F0[e])));
            float d1 = fmaf(m10, P0[e], fmaf(m11, P1[e], fmaf(m12, P2[e], t1 - F1[e])));
            float d2 = fmaf(m20, P0[e], fmaf(m21, P1[e], fmaf(m22, P2[e], t2 - F2[e])));
            float sq = fmaf(d0, d0, fmaf(d1, d1, d2 * d2));
            accp[e]  = fmaf(MK[e], sq, accp[e]);
        }
    }

    float acc = 0.f;
    #pragma unroll
    for (int e = 0; e < 4; ++e) {
        float sig = fmaf(0.5f * F0[e], F0[e],
                    fmaf(0.5f * F1[e], F1[e],
                    fmaf(0.5f * F2[e], F2[e], EPS)));
        acc += accp[e] / sig;
    }

    #pragma unroll
    for (int off = 32; off > 0; off >>= 1) acc += __shfl_down(acc, off);
    if ((tid & 63) == 0) sWave[tid >> 6] = acc;
    __syncthreads();
    if (tid == 0) {
        float s = (sWave[0] + sWave[1]) + (sWave[2] + sWave[3]);
        partials[blockIdx.y * gridDim.x + blockIdx.x] = s;
    }
}

__global__ __launch_bounds__(256) void reduce_kernel(
    const float* __restrict__ partials, float* __restrict__ out)
{
    __shared__ float sWave[4];
    const int tid = threadIdx.x;

    float acc = 0.f;
    for (int i = tid; i < NPARTIAL; i += 256) acc += partials[i];

    #pragma unroll
    for (int off = 32; off > 0; off >>= 1) acc += __shfl_down(acc, off);
    if ((tid & 63) == 0) sWave[tid >> 6] = acc;
    __syncthreads();
    if (tid == 0) {
        float s = (sWave[0] + sWave[1]) + (sWave[2] + sWave[3]);
        out[0] = s * SCALE;
    }
}

extern "C" void kernel_launch(void* const* d_in, const int* in_sizes, int n_in,
                              void* d_out, int out_size, void* d_ws, size_t ws_size,
                              hipStream_t stream) {
    const float* pts   = (const float*)d_in[0];
    const float* masks = (const float*)d_in[1];
    const float* tfms  = (const float*)d_in[2];
    const float* flows = (const float*)d_in[3];
    float* out      = (float*)d_out;
    float* partials = (float*)d_ws;

    dim3 grid(BLOCKS_X, BATCH);        // (75, 32) = 2400 blocks
    w3d_loss_kernel<<<grid, 256, 0, stream>>>(pts, masks, tfms, flows, partials);
    reduce_kernel<<<1, 256, 0, stream>>>(partials, out);
}

// Round 9
// 156.695 us; speedup vs baseline: 1.1043x; 1.0470x over previous
//
#include <hip/hip_runtime.h>

// Weighted3DTransformNormLoss — MI355X (gfx950)
// loss = 0.5/size * sum_{b,k,h,w} mask * ||(R-I)p + (t - tf)||^2 / (0.5||tf||^2 + eps)
//
// R8 (resubmit after broker timeout): R7 (asm-fence MLP, fastest so far at
// 47.4us) + NONTEMPORAL loads. Theory: demand reads are MSHR-bound
// (~64 lines/CU x 64B / ~850cyc = ~4.7 B/cyc/CU = 2.9 TB/s device-wide,
// exactly what we observe and exactly the m13 copy's read rate). nt loads
// may bypass the L1-side tracking.

typedef float f32x4 __attribute__((ext_vector_type(4)));

constexpr int BATCH = 32;
constexpr int KK    = 8;
constexpr int H     = 240;
constexpr int W     = 320;
constexpr int HW    = H * W;                 // 76800
constexpr float EPS = 0.001f;
constexpr float SCALE = 0.5f / (float)(BATCH * 3 * HW);

constexpr int PIX_PER_THREAD = 4;
constexpr int BLOCKS_X = HW / (256 * PIX_PER_THREAD);    // 75
constexpr int NPARTIAL = BLOCKS_X * BATCH;               // 2400

__device__ __forceinline__ f32x4 ntload(const float* p) {
    return __builtin_nontemporal_load((const f32x4*)p);
}

__global__ __launch_bounds__(256, 4) void w3d_loss_kernel(
    const float* __restrict__ pts,     // [B,3,H,W]
    const float* __restrict__ masks,   // [B,K,H,W]
    const float* __restrict__ tfms,    // [B,K,3,4]
    const float* __restrict__ flows,   // [B,3,H,W]
    float* __restrict__ partials)      // [NPARTIAL]
{
    __shared__ float sT[KK * 12];
    __shared__ float sWave[4];

    const int b   = blockIdx.y;
    const int tid = threadIdx.x;

    if (tid < KK * 12) {
        float v = tfms[b * KK * 12 + tid];
        int j  = tid % 12;
        int i  = j >> 2;
        int jj = j & 3;
        if (jj < 3 && i == jj) v -= 1.0f;
        sT[tid] = v;
    }
    __syncthreads();

    const int base = (blockIdx.x * 256 + tid) * PIX_PER_THREAD;
    const float* pb = pts   + (size_t)b * 3  * HW;
    const float* fb = flows + (size_t)b * 3  * HW;
    const float* mb = masks + (size_t)b * KK * HW;

    // ---- issue ALL 14 nontemporal float4 loads; first use is the asm fence ----
    f32x4 p0 = ntload(pb + 0 * HW + base);
    f32x4 p1 = ntload(pb + 1 * HW + base);
    f32x4 p2 = ntload(pb + 2 * HW + base);
    f32x4 f0 = ntload(fb + 0 * HW + base);
    f32x4 f1 = ntload(fb + 1 * HW + base);
    f32x4 f2 = ntload(fb + 2 * HW + base);
    f32x4 m0 = ntload(mb + 0 * HW + base);
    f32x4 m1 = ntload(mb + 1 * HW + base);
    f32x4 m2 = ntload(mb + 2 * HW + base);
    f32x4 m3 = ntload(mb + 3 * HW + base);
    f32x4 m4 = ntload(mb + 4 * HW + base);
    f32x4 m5 = ntload(mb + 5 * HW + base);
    f32x4 m6 = ntload(mb + 6 * HW + base);
    f32x4 m7 = ntload(mb + 7 * HW + base);

    asm volatile("" ::
        "v"(p0), "v"(p1), "v"(p2), "v"(f0), "v"(f1), "v"(f2),
        "v"(m0), "v"(m1), "v"(m2), "v"(m3), "v"(m4), "v"(m5), "v"(m6), "v"(m7));

    const float P0[4] = {p0.x, p0.y, p0.z, p0.w};
    const float P1[4] = {p1.x, p1.y, p1.z, p1.w};
    const float P2[4] = {p2.x, p2.y, p2.z, p2.w};
    const float F0[4] = {f0.x, f0.y, f0.z, f0.w};
    const float F1[4] = {f1.x, f1.y, f1.z, f1.w};
    const float F2[4] = {f2.x, f2.y, f2.z, f2.w};
    const f32x4 MKV[KK] = {m0, m1, m2, m3, m4, m5, m6, m7};

    float accp[4] = {0.f, 0.f, 0.f, 0.f};

    #pragma unroll
    for (int k = 0; k < KK; ++k) {
        const float m00 = sT[k*12+0], m01 = sT[k*12+1], m02 = sT[k*12+2],  t0 = sT[k*12+3];
        const float m10 = sT[k*12+4], m11 = sT[k*12+5], m12 = sT[k*12+6],  t1 = sT[k*12+7];
        const float m20 = sT[k*12+8], m21 = sT[k*12+9], m22 = sT[k*12+10], t2 = sT[k*12+11];
        const float MK[4] = {MKV[k].x, MKV[k].y, MKV[k].z, MKV[k].w};

        #pragma unroll
        for (int e = 0; e < 4; ++e) {
            float d0 = fmaf(m00, P0[e], fmaf(m01, P1[e], fmaf(m02, P2[e], t0 - F0[e])));
            float d1 = fmaf(m10, P0[e], fmaf(m11, P1[e], fmaf(m12, P2[e], t1 - F1[e])));
            float d2 = fmaf(m20, P0[e], fmaf(m21, P1[e], fmaf(m22, P2[e], t2 - F2[e])));
            float sq = fmaf(d0, d0, fmaf(d1, d1, d2 * d2));
            accp[e]  = fmaf(MK[e], sq, accp[e]);
        }
    }

    float acc = 0.f;
    #pragma unroll
    for (int e = 0; e < 4; ++e) {
        float sig = fmaf(0.5f * F0[e], F0[e],
                    fmaf(0.5f * F1[e], F1[e],
                    fmaf(0.5f * F2[e], F2[e], EPS)));
        acc += accp[e] / sig;
    }

    #pragma unroll
    for (int off = 32; off > 0; off >>= 1) acc += __shfl_down(acc, off);
    if ((tid & 63) == 0) sWave[tid >> 6] = acc;
    __syncthreads();
    if (tid == 0) {
        float s = (sWave[0] + sWave[1]) + (sWave[2] + sWave[3]);
        partials[blockIdx.y * gridDim.x + blockIdx.x] = s;
    }
}

__global__ __launch_bounds__(256) void reduce_kernel(
    const float* __restrict__ partials, float* __restrict__ out)
{
    __shared__ float sWave[4];
    const int tid = threadIdx.x;

    float acc = 0.f;
    for (int i = tid; i < NPARTIAL; i += 256) acc += partials[i];

    #pragma unroll
    for (int off = 32; off > 0; off >>= 1) acc += __shfl_down(acc, off);
    if ((tid & 63) == 0) sWave[tid >> 6] = acc;
    __syncthreads();
    if (tid == 0) {
        float s = (sWave[0] + sWave[1]) + (sWave[2] + sWave[3]);
        out[0] = s * SCALE;
    }
}

extern "C" void kernel_launch(void* const* d_in, const int* in_sizes, int n_in,
                              void* d_out, int out_size, void* d_ws, size_t ws_size,
                              hipStream_t stream) {
    const float* pts   = (const float*)d_in[0];
    const float* masks = (const float*)d_in[1];
    const float* tfms  = (const float*)d_in[2];
    const float* flows = (const float*)d_in[3];
    float* out      = (float*)d_out;
    float* partials = (float*)d_ws;

    dim3 grid(BLOCKS_X, BATCH);        // (75, 32) = 2400 blocks
    w3d_loss_kernel<<<grid, 256, 0, stream>>>(pts, masks, tfms, flows, partials);
    reduce_kernel<<<1, 256, 0, stream>>>(partials, out);
}